// Round 1
// baseline (98.271 us; speedup 1.0000x reference)
//
#include <hip/hip_runtime.h>

// QuantizedSoftmax2: rows of 1024, integer-valued fp32 input.
//   d   = (int)(x - rowmax) + 2*eb                (exact: int-valued fp32 diff)
//   exp = (d >= 0) ? 2^d : 0                      (exact powers of two)
//   S   = sum(exp)  -- exact in uint32 (<= 2^26)
//   k   = round_half_even( fp32( log2(S) ) )      (emulates np.round(np.log2))
//   out = (d - k >= -eb) ? 2^(d - k) : 0          (floor(2^d * 2^-(k-eb)) * 2^-eb)
__global__ __launch_bounds__(256) void qsm_kernel(const float* __restrict__ x,
                                                  const int* __restrict__ ebp,
                                                  float* __restrict__ out,
                                                  int n_rows) {
    const int eb   = ebp[0];            // 8
    const int wave = threadIdx.x >> 6;  // 4 waves/block, 1 row/wave
    const int lane = threadIdx.x & 63;
    const int row  = (blockIdx.x << 2) + wave;
    if (row >= n_rows) return;

    const float* __restrict__ xr  = x   + (size_t)row * 1024;
    float*       __restrict__ outr = out + (size_t)row * 1024;

    // 16 elements per lane; instruction q covers contiguous 1 KiB [q*256, q*256+256)
    float v[16];
    #pragma unroll
    for (int q = 0; q < 4; ++q) {
        float4 t = *reinterpret_cast<const float4*>(xr + q * 256 + lane * 4);
        v[q * 4 + 0] = t.x; v[q * 4 + 1] = t.y;
        v[q * 4 + 2] = t.z; v[q * 4 + 3] = t.w;
    }

    // row max: lane-local then 6-step wave butterfly (exact, fp32)
    float m = v[0];
    #pragma unroll
    for (int i = 1; i < 16; ++i) m = fmaxf(m, v[i]);
    #pragma unroll
    for (int s = 1; s < 64; s <<= 1) m = fmaxf(m, __shfl_xor(m, s, 64));

    // exact integer sum of 2^d
    const int twoeb = eb + eb;
    int d[16];
    unsigned int ssum = 0u;
    #pragma unroll
    for (int i = 0; i < 16; ++i) {
        const int dd = (int)(v[i] - m) + twoeb;   // exact: both integer-valued
        d[i] = dd;
        if (dd >= 0) ssum += (1u << dd);
    }
    #pragma unroll
    for (int s = 1; s < 64; s <<= 1) ssum += __shfl_xor(ssum, s, 64);

    // k = np.round(np.log2(S)) in fp32 semantics, half-to-even via rintf
    const float lv = (float)log2((double)ssum);
    const int   k  = (int)rintf(lv);
    const int   lo = -eb;

    // out = 2^(d-k) when d-k >= -eb else 0; exponent in [-eb, 0] -> bit-construct
    #pragma unroll
    for (int q = 0; q < 4; ++q) {
        float4 o;
        {
            const int e0 = d[q * 4 + 0] - k;
            const int e1 = d[q * 4 + 1] - k;
            const int e2 = d[q * 4 + 2] - k;
            const int e3 = d[q * 4 + 3] - k;
            o.x = __uint_as_float(e0 >= lo ? (unsigned int)(127 + e0) << 23 : 0u);
            o.y = __uint_as_float(e1 >= lo ? (unsigned int)(127 + e1) << 23 : 0u);
            o.z = __uint_as_float(e2 >= lo ? (unsigned int)(127 + e2) << 23 : 0u);
            o.w = __uint_as_float(e3 >= lo ? (unsigned int)(127 + e3) << 23 : 0u);
        }
        *reinterpret_cast<float4*>(outr + q * 256 + lane * 4) = o;
    }
}

extern "C" void kernel_launch(void* const* d_in, const int* in_sizes, int n_in,
                              void* d_out, int out_size, void* d_ws, size_t ws_size,
                              hipStream_t stream) {
    const float* x  = (const float*)d_in[0];
    const int*   eb = (const int*)d_in[1];
    float*       o  = (float*)d_out;
    const int n_rows = in_sizes[0] >> 10;          // last axis = 1024
    const int blocks = (n_rows + 3) >> 2;          // 4 rows per 256-thread block
    hipLaunchKernelGGL(qsm_kernel, dim3(blocks), dim3(256), 0, stream,
                       x, eb, o, n_rows);
}

// Round 3
// 88.201 us; speedup vs baseline: 1.1142x; 1.1142x over previous
//
#include <hip/hip_runtime.h>

// QuantizedSoftmax2: rows of 1024, integer-valued fp32 input.
//   d   = (int)(x - rowmax) + 2*eb                (exact: int-valued fp32 diff)
//   exp = (d >= 0) ? 2^d : 0                      (exact powers of two)
//   S   = sum(exp)  -- exact in uint32 (<= 2^26)
//   k   = round_half_even( fp32( log2(S) ) )      (emulates np.round(np.log2))
//   out = (d - k >= -eb) ? 2^(d - k) : 0          (floor(2^d * 2^-(k-eb)) * 2^-eb)
//
// R2: nontemporal loads/stores via native clang vector type (HIP_vector_type
// is a struct and rejected by the builtin; ext_vector_type(4) float works).
typedef float f32x4 __attribute__((ext_vector_type(4)));

__global__ __launch_bounds__(256) void qsm_kernel(const float* __restrict__ x,
                                                  const int* __restrict__ ebp,
                                                  float* __restrict__ out,
                                                  int n_rows) {
    const int eb   = ebp[0];            // 8
    const int wave = threadIdx.x >> 6;  // 4 waves/block, 1 row/wave
    const int lane = threadIdx.x & 63;
    const int row  = (blockIdx.x << 2) + wave;
    if (row >= n_rows) return;

    const f32x4* __restrict__ xr =
        reinterpret_cast<const f32x4*>(x + (size_t)row * 1024) + lane;
    f32x4* __restrict__ outr =
        reinterpret_cast<f32x4*>(out + (size_t)row * 1024) + lane;

    // 16 elements per lane; vector q covers contiguous 1 KiB [q*256, q*256+256)
    float v[16];
    #pragma unroll
    for (int q = 0; q < 4; ++q) {
        f32x4 t = __builtin_nontemporal_load(xr + q * 64);
        v[q * 4 + 0] = t.x; v[q * 4 + 1] = t.y;
        v[q * 4 + 2] = t.z; v[q * 4 + 3] = t.w;
    }

    // row max: lane-local then 6-step wave butterfly (exact, fp32)
    float m = v[0];
    #pragma unroll
    for (int i = 1; i < 16; ++i) m = fmaxf(m, v[i]);
    #pragma unroll
    for (int s = 1; s < 64; s <<= 1) m = fmaxf(m, __shfl_xor(m, s, 64));

    // exact integer sum of 2^d
    const int twoeb = eb + eb;
    int d[16];
    unsigned int ssum = 0u;
    #pragma unroll
    for (int i = 0; i < 16; ++i) {
        const int dd = (int)(v[i] - m) + twoeb;   // exact: both integer-valued
        d[i] = dd;
        if (dd >= 0) ssum += (1u << dd);
    }
    #pragma unroll
    for (int s = 1; s < 64; s <<= 1) ssum += __shfl_xor(ssum, s, 64);

    // k = np.round(np.log2(S)) in fp32 semantics, half-to-even via rintf
    const float lv = (float)log2((double)ssum);
    const int   k  = (int)rintf(lv);
    const int   lo = -eb;

    // out = 2^(d-k) when d-k >= -eb else 0; exponent in [-eb, 0] -> bit-construct
    #pragma unroll
    for (int q = 0; q < 4; ++q) {
        f32x4 o;
        {
            const int e0 = d[q * 4 + 0] - k;
            const int e1 = d[q * 4 + 1] - k;
            const int e2 = d[q * 4 + 2] - k;
            const int e3 = d[q * 4 + 3] - k;
            o.x = __uint_as_float(e0 >= lo ? (unsigned int)(127 + e0) << 23 : 0u);
            o.y = __uint_as_float(e1 >= lo ? (unsigned int)(127 + e1) << 23 : 0u);
            o.z = __uint_as_float(e2 >= lo ? (unsigned int)(127 + e2) << 23 : 0u);
            o.w = __uint_as_float(e3 >= lo ? (unsigned int)(127 + e3) << 23 : 0u);
        }
        __builtin_nontemporal_store(o, outr + q * 64);
    }
}

extern "C" void kernel_launch(void* const* d_in, const int* in_sizes, int n_in,
                              void* d_out, int out_size, void* d_ws, size_t ws_size,
                              hipStream_t stream) {
    const float* x  = (const float*)d_in[0];
    const int*   eb = (const int*)d_in[1];
    float*       o  = (float*)d_out;
    const int n_rows = in_sizes[0] >> 10;          // last axis = 1024
    const int blocks = (n_rows + 3) >> 2;          // 4 rows per 256-thread block
    hipLaunchKernelGGL(qsm_kernel, dim3(blocks), dim3(256), 0, stream,
                       x, eb, o, n_rows);
}